// Round 1
// baseline (14.789 us; speedup 1.0000x reference)
//
#include <hip/hip_runtime.h>

// out[i,n,o] = sum_{kh,b,kj} w[i,kh,b,kj] * T3(kh,n,b,kj,o)
// t4[kh,b,j | n] = maskload x[b, n+kh-1, j] + maskload x[64+b, ((n-1)%14)+kh-1, j]
// T3 = t4[kh,b,(o+kj-2)%14] if 0 <= o+kj-1 < 14 else 0

#define WROW 580   // LDS stride per i-row: 576 + 4 pad floats (il*4 mod 32 banks)
#define TJ   68    // LDS stride per (kh,j) row of t4: 64 + 4 pad floats

__global__ __launch_bounds__(256) void fused_conv_kernel(
    const float* __restrict__ x,   // (128,14,14)
    const float* __restrict__ w,   // (256,3,64,3)
    float* __restrict__ out)       // (256,14,14)
{
    __shared__ __align__(16) float wl[16 * WROW];        // w slice, layout [il][kh*3+kj][b]
    __shared__ __align__(16) float t4l[3 * 14 * TJ];     // t4 row,  layout [kh][j][b]

    const int n  = blockIdx.x;       // output row 0..13
    const int i0 = blockIdx.y * 16;  // i-tile base (16 tiles)
    const int t  = threadIdx.x;

    // ---- stage w slice (16 rows x 576), transposed so b is contiguous ----
    for (int p = t; p < 16 * 576; p += 256) {
        const int il = p / 576;
        const int q  = p % 576;          // = kh*192 + b*3 + kj
        const int kh = q / 192;
        const int r  = q % 192;
        const int b  = r / 3;
        const int kj = r % 3;
        wl[il * WROW + (kh * 3 + kj) * 64 + b] = w[(i0 + il) * 576 + q];
    }

    // ---- build t4 row for this n: t4l[kh][j][b] ----
    const int hh = (n + 13) % 14;        // (n-1) mod 14
    for (int p = t; p < 3 * 64 * 14; p += 256) {
        const int kh = p / (64 * 14);
        const int r  = p % (64 * 14);
        const int b  = r / 14;
        const int j  = r % 14;
        const int r0 = n + kh - 1;
        const int r1 = hh + kh - 1;
        float v = 0.f;
        if (r0 >= 0 && r0 < 14) v += x[b * 196 + r0 * 14 + j];
        if (r1 >= 0 && r1 < 14) v += x[(64 + b) * 196 + r1 * 14 + j];
        t4l[(kh * 14 + j) * TJ + b] = v;
    }
    __syncthreads();

    // ---- main: thread (il = t>>4, o = t&15) computes out[i0+il, n, o] ----
    const int il = t >> 4;
    const int o  = t & 15;
    if (o >= 14) return;                 // 2 idle o-slots per il

    float4 acc = {0.f, 0.f, 0.f, 0.f};
    #pragma unroll
    for (int kh = 0; kh < 3; ++kh) {
        #pragma unroll
        for (int kj = 0; kj < 3; ++kj) {
            const int jp = o + kj - 1;               // second-unfold index
            if (jp < 0 || jp >= 14) continue;        // zero-pad mask
            const int j = (jp == 0) ? 13 : jp - 1;   // (o+kj-2) mod 14  (the +1 roll)
            const float4* wp = reinterpret_cast<const float4*>(&wl[il * WROW + (kh * 3 + kj) * 64]);
            const float4* tp = reinterpret_cast<const float4*>(&t4l[(kh * 14 + j) * TJ]);
            #pragma unroll
            for (int b4 = 0; b4 < 16; ++b4) {
                const float4 wv = wp[b4];
                const float4 tv = tp[b4];
                acc.x += wv.x * tv.x;
                acc.y += wv.y * tv.y;
                acc.z += wv.z * tv.z;
                acc.w += wv.w * tv.w;
            }
        }
    }
    out[(i0 + il) * 196 + n * 14 + o] = acc.x + acc.y + acc.z + acc.w;
}

extern "C" void kernel_launch(void* const* d_in, const int* in_sizes, int n_in,
                              void* d_out, int out_size, void* d_ws, size_t ws_size,
                              hipStream_t stream) {
    const float* x   = (const float*)d_in[0];   // 25088 floats
    const float* w   = (const float*)d_in[1];   // 147456 floats
    float*       out = (float*)d_out;           // 50176 floats

    dim3 grid(14, 16);   // (n, i-tile)
    fused_conv_kernel<<<grid, 256, 0, stream>>>(x, w, out);
}

// Round 2
// 14.499 us; speedup vs baseline: 1.0200x; 1.0200x over previous
//
#include <hip/hip_runtime.h>

// out[i,n,o] = sum_{kh,b,kj} w[i,kh,b,kj] * T3(kh,n,b,kj,o)
// t4[kh,b,j | n] = maskload x[b, n+kh-1, j] + maskload x[64+b, ((n-1)%14)+kh-1, j]
// T3 = t4[kh,b,(o+kj-2)%14] if 0 <= o+kj-1 < 14 else 0

#define WROW 580   // LDS stride per i-row: 576 + 4 pad floats
#define TJ   68    // LDS stride per (kh,j) row of t4: 64 + 4 pad floats

__global__ __launch_bounds__(256) void fused_conv_kernel(
    const float* __restrict__ x,   // (128,14,14)
    const float* __restrict__ w,   // (256,3,64,3)
    float* __restrict__ out)       // (256,14,14)
{
    __shared__ __align__(16) float wl[8 * WROW];         // w slice, layout [il][kh*3+kj][b]
    __shared__ __align__(16) float t4l[3 * 14 * TJ];     // t4 row,  layout [kh][j][b]

    const int n  = blockIdx.x;       // output row 0..13
    const int i0 = blockIdx.y * 8;   // i-tile base (32 tiles)
    const int t  = threadIdx.x;

    // ---- stage w slice (8 rows x 576) transposed: coalesced float4 reads,
    //      4 scattered ds_write_b32 each ----
    for (int p = t; p < 8 * 144; p += 256) {            // 144 float4 per i-row
        const int il = p / 144;
        const int m  = p % 144;
        const float4 v = reinterpret_cast<const float4*>(w + (i0 + il) * 576)[m];
        const float vv[4] = {v.x, v.y, v.z, v.w};
        #pragma unroll
        for (int e = 0; e < 4; ++e) {
            const int q  = 4 * m + e;        // = kh*192 + b*3 + kj
            const int kh = q / 192;
            const int r  = q % 192;
            const int b  = r / 3;
            const int kj = r % 3;
            wl[il * WROW + (kh * 3 + kj) * 64 + b] = vv[e];
        }
    }

    // ---- build t4 row for this n: t4l[kh][j][b] ----
    const int hh = (n + 13) % 14;        // (n-1) mod 14
    for (int p = t; p < 3 * 64 * 14; p += 256) {
        const int kh = p / (64 * 14);
        const int r  = p % (64 * 14);
        const int b  = r / 14;
        const int j  = r % 14;
        const int r0 = n + kh - 1;
        const int r1 = hh + kh - 1;
        float v = 0.f;
        if (r0 >= 0 && r0 < 14) v += x[b * 196 + r0 * 14 + j];
        if (r1 >= 0 && r1 < 14) v += x[(64 + b) * 196 + r1 * 14 + j];
        t4l[(kh * 14 + j) * TJ + b] = v;
    }
    __syncthreads();

    // ---- main: lane pair (h=0/1) splits the 64 b-channels of one output ----
    const int il = t >> 5;          // 0..7
    const int o  = (t >> 1) & 15;   // 0..15 (14 used)
    const int h  = t & 1;           // reduction half
    if (o >= 14) return;

    float4 acc = {0.f, 0.f, 0.f, 0.f};
    #pragma unroll
    for (int kh = 0; kh < 3; ++kh) {
        #pragma unroll
        for (int kj = 0; kj < 3; ++kj) {
            const int jp = o + kj - 1;               // second-unfold index
            if (jp < 0 || jp >= 14) continue;        // zero-pad mask
            const int j = (jp == 0) ? 13 : jp - 1;   // (o+kj-2) mod 14
            const float4* wp = reinterpret_cast<const float4*>(&wl[il * WROW + (kh * 3 + kj) * 64]);
            const float4* tp = reinterpret_cast<const float4*>(&t4l[(kh * 14 + j) * TJ]);
            #pragma unroll
            for (int c = 0; c < 2; ++c) {
                #pragma unroll
                for (int k = 0; k < 4; ++k) {
                    const int b4 = c * 8 + h * 4 + k;   // bank-group interleave
                    const float4 wv = wp[b4];
                    const float4 tv = tp[b4];
                    acc.x += wv.x * tv.x;
                    acc.y += wv.y * tv.y;
                    acc.z += wv.z * tv.z;
                    acc.w += wv.w * tv.w;
                }
            }
        }
    }
    float s = acc.x + acc.y + acc.z + acc.w;
    s += __shfl_xor(s, 1);                            // combine lane pair
    if (h == 0) out[(i0 + il) * 196 + n * 14 + o] = s;
}

extern "C" void kernel_launch(void* const* d_in, const int* in_sizes, int n_in,
                              void* d_out, int out_size, void* d_ws, size_t ws_size,
                              hipStream_t stream) {
    const float* x   = (const float*)d_in[0];   // 25088 floats
    const float* w   = (const float*)d_in[1];   // 147456 floats
    float*       out = (float*)d_out;           // 50176 floats

    dim3 grid(14, 32);   // (n, i-tile of 8)
    fused_conv_kernel<<<grid, 256, 0, stream>>>(x, w, out);
}

// Round 3
// 14.244 us; speedup vs baseline: 1.0383x; 1.0179x over previous
//
#include <hip/hip_runtime.h>

// out[i,n,o] = sum_{kh,b,kj} w[i,kh,b,kj] * T3(kh,n,b,kj,o)
// t4[kh,b,j | n] = maskload x[b, n+kh-1, j] + maskload x[64+b, ((n-1)%14)+kh-1, j]
// T3 = t4[kh,b,(o+kj-2)%14] if 0 <= o+kj-1 < 14 else 0

#define WROW 580   // LDS stride per i-row: 576 + 4 pad floats
#define TJ   68    // LDS stride per (kh,j) row of t4: 64 + 4 pad floats

__global__ __launch_bounds__(256) void fused_conv_kernel(
    const float* __restrict__ x,   // (128,14,14)
    const float* __restrict__ w,   // (256,3,64,3)
    float* __restrict__ out)       // (256,14,14)
{
    __shared__ __align__(16) float wl[4 * WROW];         // w slice, layout [il][kh*3+kj][b]
    __shared__ __align__(16) float t4l[3 * 14 * TJ];     // t4 row,  layout [kh][j][b]

    const int n  = blockIdx.x;       // output row 0..13
    const int i0 = blockIdx.y * 4;   // i-tile base (64 tiles)
    const int t  = threadIdx.x;

    // ---- build t4 row for this n: t4l[kh][j][b]  (longest-latency loads first) ----
    const int hh = (n + 13) % 14;        // (n-1) mod 14
    for (int p = t; p < 3 * 64 * 14; p += 256) {
        const int kh = p / (64 * 14);
        const int r  = p % (64 * 14);
        const int b  = r / 14;
        const int j  = r % 14;
        const int r0 = n + kh - 1;
        const int r1 = hh + kh - 1;
        float v = 0.f;
        if (r0 >= 0 && r0 < 14) v += x[b * 196 + r0 * 14 + j];
        if (r1 >= 0 && r1 < 14) v += x[(64 + b) * 196 + r1 * 14 + j];
        t4l[(kh * 14 + j) * TJ + b] = v;
    }

    // ---- stage w slice (4 rows x 576) transposed: coalesced float4 reads ----
    for (int p = t; p < 4 * 144; p += 256) {            // 144 float4 per i-row
        const int il = p / 144;
        const int m  = p % 144;
        const float4 v = reinterpret_cast<const float4*>(w + (i0 + il) * 576)[m];
        const float vv[4] = {v.x, v.y, v.z, v.w};
        #pragma unroll
        for (int e = 0; e < 4; ++e) {
            const int q  = 4 * m + e;        // = kh*192 + b*3 + kj
            const int kh = q / 192;
            const int r  = q % 192;
            const int b  = r / 3;
            const int kj = r % 3;
            wl[il * WROW + (kh * 3 + kj) * 64 + b] = vv[e];
        }
    }
    __syncthreads();

    // ---- main: 4-way reduction split over the 64 b-channels ----
    const int il = t >> 6;          // 0..3
    const int o  = (t >> 2) & 15;   // 0..15 (14 used)
    const int h  = t & 3;           // reduction quarter
    if (o >= 14) return;

    float4 acc = {0.f, 0.f, 0.f, 0.f};
    #pragma unroll
    for (int kh = 0; kh < 3; ++kh) {
        #pragma unroll
        for (int kj = 0; kj < 3; ++kj) {
            const int jp = o + kj - 1;               // second-unfold index
            if (jp < 0 || jp >= 14) continue;        // zero-pad mask
            const int j = (jp == 0) ? 13 : jp - 1;   // (o+kj-2) mod 14
            const float4* wp = reinterpret_cast<const float4*>(&wl[il * WROW + (kh * 3 + kj) * 64]);
            const float4* tp = reinterpret_cast<const float4*>(&t4l[(kh * 14 + j) * TJ]);
            #pragma unroll
            for (int k = 0; k < 4; ++k) {
                const int b4 = h + 4 * k;            // stride-4 interleave over quarters
                const float4 wv = wp[b4];
                const float4 tv = tp[b4];
                acc.x += wv.x * tv.x;
                acc.y += wv.y * tv.y;
                acc.z += wv.z * tv.z;
                acc.w += wv.w * tv.w;
            }
        }
    }
    float s = acc.x + acc.y + acc.z + acc.w;
    s += __shfl_xor(s, 1);                            // combine h pairs
    s += __shfl_xor(s, 2);                            // combine h quads
    if (h == 0) out[(i0 + il) * 196 + n * 14 + o] = s;
}

extern "C" void kernel_launch(void* const* d_in, const int* in_sizes, int n_in,
                              void* d_out, int out_size, void* d_ws, size_t ws_size,
                              hipStream_t stream) {
    const float* x   = (const float*)d_in[0];   // 25088 floats
    const float* w   = (const float*)d_in[1];   // 147456 floats
    float*       out = (float*)d_out;           // 50176 floats

    dim3 grid(14, 64);   // (n, i-tile of 4)
    fused_conv_kernel<<<grid, 256, 0, stream>>>(x, w, out);
}